// Round 13
// baseline (980.371 us; speedup 1.0000x reference)
//
#include <hip/hip_runtime.h>
#include <hip/hip_bf16.h>

// Performer (FAVOR+) classifier, round 12: chunked LDS staging in k_attn (4 blocks/CU).
// DEPTH=4, HEADS=2, DH=32, DE=64, N=16384, B=8, F=110

constexpr int B_   = 8;
constexpr int N_   = 16384;
constexpr int F_   = 110;
constexpr int NTOK = B_ * N_;          // 131072
constexpr int WSEG = 52736;            // per-layer f16 weight-plane elems
constexpr int CTXE = 16 * 32 * 112;    // ctxT elems (f padded to 112)
constexpr float DN    = 0.42044820762685725f;   // 32^-0.25
constexpr float RATIO = 0.09534625892455922f;   // 110^-0.5
constexpr float KEPS  = 1e-4f;

typedef _Float16 f16x8 __attribute__((ext_vector_type(8)));
typedef float    f32x4 __attribute__((ext_vector_type(4)));

__device__ __forceinline__ float wsum64(float v) {
#pragma unroll
  for (int m = 32; m > 0; m >>= 1) v += __shfl_xor(v, m);
  return v;
}
__device__ __forceinline__ float wmax64(float v) {
#pragma unroll
  for (int m = 32; m > 0; m >>= 1) v = fmaxf(v, __shfl_xor(v, m));
  return v;
}
__device__ __forceinline__ float rsum16(float v) {
  v += __shfl_xor(v, 1); v += __shfl_xor(v, 2);
  v += __shfl_xor(v, 4); v += __shfl_xor(v, 8);
  return v;
}
__device__ __forceinline__ float rmax16(float v) {
  v = fmaxf(v, __shfl_xor(v, 1)); v = fmaxf(v, __shfl_xor(v, 2));
  v = fmaxf(v, __shfl_xor(v, 4)); v = fmaxf(v, __shfl_xor(v, 8));
  return v;
}

// ---------------- h = concat(emb_w, x) ----------------
__global__ __launch_bounds__(256) void k_embed(const float* __restrict__ x,
                                               const float* __restrict__ emb,
                                               float* __restrict__ hbuf) {
  int gidx = blockIdx.x * 256 + threadIdx.x;
  int tok = gidx >> 6, c = gidx & 63;
  float v;
  if (c < 63) v = emb[(size_t)(tok & (N_ - 1)) * 63 + c];
  else        v = x[tok];
  hbuf[gidx] = v;
}

// ------ weight prep: wo/w1/w2/wq/proj^T/wk/wv -> hi/lo f16 B-frag planes ------
__global__ __launch_bounds__(256) void k_prep(
    const float* __restrict__ wo, const float* __restrict__ w1, const float* __restrict__ w2,
    const float* __restrict__ wq, const float* __restrict__ proj,
    const float* __restrict__ wk, const float* __restrict__ wv,
    _Float16* __restrict__ whi, _Float16* __restrict__ wlo) {
  int t = blockIdx.x * 256 + threadIdx.x;
  if (t >= 4 * WSEG) return;
  int l = t / WSEG, r = t % WSEG;
  int rr = r; const float* src; int N; bool tr = false;
  if (rr < 4096)       { src = wo + l * 4096;  N = 64; }
  else if (rr < 20480) { src = w1 + l * 16384; N = 256; rr -= 4096; }
  else if (rr < 36864) { src = w2 + l * 16384; N = 64;  rr -= 20480; }
  else if (rr < 40960) { src = wq + l * 4096;  N = 64;  rr -= 36864; }
  else if (rr < 44544) { src = proj + l * 3520; N = 112; tr = true; rr -= 40960; }
  else if (rr < 48640) { src = wk + l * 4096;  N = 64;  rr -= 44544; }
  else                 { src = wv + l * 4096;  N = 64;  rr -= 48640; }
  int f = rr >> 9, lane = (rr >> 3) & 63, e = rr & 7;
  int NB = N >> 4;
  int k = (f / NB) * 32 + ((lane >> 4) & 3) * 8 + e;
  int n = (f % NB) * 16 + (lane & 15);
  float v;
  if (tr) v = (n < F_) ? src[n * 32 + k] : 0.f;
  else    v = src[k * N + n];
  _Float16 hi = (_Float16)v;
  _Float16 lo = (_Float16)(v - (float)hi);
  size_t off = (size_t)l * WSEG + r;
  whi[off] = hi; wlo[off] = lo;
}

// ------ ctxT[d][f] -> B-frag hi/lo planes (K=f padded to 128, N=d 32) per (b,head) ------
__global__ __launch_bounds__(256) void k_ctxprep(const float* __restrict__ ctxT_g,
                                                 _Float16* __restrict__ ctxBh,
                                                 _Float16* __restrict__ ctxBl) {
  int t = blockIdx.x * 256 + threadIdx.x;        // 65536 = 16 bh * 8 frag * 64 lane * 8 e
  int e = t & 7, lane = (t >> 3) & 63, frag = (t >> 9) & 7, bh = t >> 12;
  int k = (frag >> 1) * 32 + ((lane >> 4) & 3) * 8 + e;   // f dim
  int n = (frag & 1) * 16 + (lane & 15);                  // d dim
  float v = (k < 112) ? ctxT_g[((size_t)bh * 32 + n) * 112 + k] : 0.f;
  _Float16 hi = (_Float16)v;
  ctxBh[t] = hi; ctxBl[t] = (_Float16)(v - (float)hi);
}

// ====== MFMA LN1 + K,V projection + global max of dd_k ======
__global__ __launch_bounds__(256) void k_ln_kv(
    const float* __restrict__ hbuf, const float* __restrict__ lng, const float* __restrict__ lnb,
    const _Float16* __restrict__ whi, const _Float16* __restrict__ wlo,  // layer base
    const float* __restrict__ bk, const float* __restrict__ bv,
    float* __restrict__ kout, float* __restrict__ vout, unsigned int* __restrict__ kmaxu) {
  __shared__ __align__(16) _Float16 kscr[4][2][16][88];   // [wave][hi/lo][row][col]
  __shared__ float wm_s[4];
  const int tid = threadIdx.x, w = tid >> 6, l = tid & 63;
  const int lr = l & 15, lg = l >> 4;
  const int row0 = blockIdx.x * 64 + w * 16;

  float hv[16];
#pragma unroll
  for (int kb = 0; kb < 2; kb++) {
    const float* hp = hbuf + (size_t)(row0 + lr) * 64 + kb * 32 + lg * 8;
    float4 p0 = *(const float4*)hp;
    float4 p1 = *(const float4*)(hp + 4);
    hv[kb * 8 + 0] = p0.x; hv[kb * 8 + 1] = p0.y; hv[kb * 8 + 2] = p0.z; hv[kb * 8 + 3] = p0.w;
    hv[kb * 8 + 4] = p1.x; hv[kb * 8 + 5] = p1.y; hv[kb * 8 + 6] = p1.z; hv[kb * 8 + 7] = p1.w;
  }
  float s = 0.f;
#pragma unroll
  for (int i = 0; i < 16; i++) s += hv[i];
  s += __shfl_xor(s, 16); s += __shfl_xor(s, 32);
  float mu1 = s * (1.f / 64.f);
  float sq = 0.f;
#pragma unroll
  for (int i = 0; i < 16; i++) { float d = hv[i] - mu1; sq += d * d; }
  sq += __shfl_xor(sq, 16); sq += __shfl_xor(sq, 32);
  float rs1 = rsqrtf(sq * (1.f / 64.f) + 1e-5f);
  f16x8 ah1[2], al1[2];
#pragma unroll
  for (int kb = 0; kb < 2; kb++) {
    const float* gp = lng + kb * 32 + lg * 8;
    const float* bp = lnb + kb * 32 + lg * 8;
    float4 g0 = *(const float4*)gp, g1 = *(const float4*)(gp + 4);
    float4 b0 = *(const float4*)bp, b1v_ = *(const float4*)(bp + 4);
    float gv[8] = {g0.x, g0.y, g0.z, g0.w, g1.x, g1.y, g1.z, g1.w};
    float bv_[8] = {b0.x, b0.y, b0.z, b0.w, b1v_.x, b1v_.y, b1v_.z, b1v_.w};
#pragma unroll
    for (int e = 0; e < 8; e++) {
      float yv = (hv[kb * 8 + e] - mu1) * rs1 * gv[e] + bv_[e];
      _Float16 hi = (_Float16)yv;
      ah1[kb][e] = hi;
      al1[kb][e] = (_Float16)(yv - (float)hi);
    }
  }
  const _Float16* wkh = whi + 44544; const _Float16* wkl = wlo + 44544;
  const _Float16* wvh = whi + 48640; const _Float16* wvl = wlo + 48640;
  f32x4 ka[4], va[4];
#pragma unroll
  for (int nt = 0; nt < 4; nt++) {
    float bb = bk[nt * 16 + lr];
    ka[nt] = f32x4{bb, bb, bb, bb};
    bb = bv[nt * 16 + lr];
    va[nt] = f32x4{bb, bb, bb, bb};
  }
#pragma unroll
  for (int kb = 0; kb < 2; kb++)
#pragma unroll
    for (int nt = 0; nt < 4; nt++) {
      int f = kb * 4 + nt;
      f16x8 bh = *(const f16x8*)(wkh + ((f * 64 + l) << 3));
      f16x8 bl = *(const f16x8*)(wkl + ((f * 64 + l) << 3));
      ka[nt] = __builtin_amdgcn_mfma_f32_16x16x32_f16(ah1[kb], bh, ka[nt], 0, 0, 0);
      ka[nt] = __builtin_amdgcn_mfma_f32_16x16x32_f16(ah1[kb], bl, ka[nt], 0, 0, 0);
      ka[nt] = __builtin_amdgcn_mfma_f32_16x16x32_f16(al1[kb], bh, ka[nt], 0, 0, 0);
      bh = *(const f16x8*)(wvh + ((f * 64 + l) << 3));
      bl = *(const f16x8*)(wvl + ((f * 64 + l) << 3));
      va[nt] = __builtin_amdgcn_mfma_f32_16x16x32_f16(ah1[kb], bh, va[nt], 0, 0, 0);
      va[nt] = __builtin_amdgcn_mfma_f32_16x16x32_f16(ah1[kb], bl, va[nt], 0, 0, 0);
      va[nt] = __builtin_amdgcn_mfma_f32_16x16x32_f16(al1[kb], bh, va[nt], 0, 0, 0);
    }
#pragma unroll
  for (int nt = 0; nt < 4; nt++)
#pragma unroll
    for (int r = 0; r < 4; r++) {
      float kd = ka[nt][r] * DN;
      size_t idx = (size_t)(row0 + lg * 4 + r) * 64 + nt * 16 + lr;
      kout[idx] = kd;
      vout[idx] = va[nt][r];
      _Float16 hi = (_Float16)kd;
      kscr[w][0][lg * 4 + r][nt * 16 + lr] = hi;
      kscr[w][1][lg * 4 + r][nt * 16 + lr] = (_Float16)(kd - (float)hi);
    }
  const _Float16* pjh = whi + 40960; const _Float16* pjl = wlo + 40960;
  float mymax = -3.0e38f;
#pragma unroll
  for (int hh = 0; hh < 2; hh++) {
    f16x8 akh = *(const f16x8*)(&kscr[w][0][lr][hh * 32 + lg * 8]);
    f16x8 akl = *(const f16x8*)(&kscr[w][1][lr][hh * 32 + lg * 8]);
#pragma unroll
    for (int nt = 0; nt < 7; nt++) {
      f32x4 dd = f32x4{0.f, 0.f, 0.f, 0.f};
      f16x8 bh = *(const f16x8*)(pjh + ((nt * 64 + l) << 3));
      f16x8 bl = *(const f16x8*)(pjl + ((nt * 64 + l) << 3));
      dd = __builtin_amdgcn_mfma_f32_16x16x32_f16(akh, bh, dd, 0, 0, 0);
      dd = __builtin_amdgcn_mfma_f32_16x16x32_f16(akh, bl, dd, 0, 0, 0);
      dd = __builtin_amdgcn_mfma_f32_16x16x32_f16(akl, bh, dd, 0, 0, 0);
      if (nt < 6 || lr < 14) {
        float m = fmaxf(fmaxf(dd[0], dd[1]), fmaxf(dd[2], dd[3]));
        mymax = fmaxf(mymax, m);
      }
    }
  }
  mymax = wmax64(mymax);
  if (l == 0) wm_s[w] = mymax;
  __syncthreads();
  if (tid == 0) {
    float m = fmaxf(fmaxf(wm_s[0], wm_s[1]), fmaxf(wm_s[2], wm_s[3]));
    unsigned u_ = __float_as_uint(m);
    unsigned mm = (u_ & 0x80000000u) ? ~u_ : (u_ | 0x80000000u);
    atomicMax(kmaxu, mm);
  }
}

// ====== MFMA kp features + ctx^T / ksum accumulation ======
__global__ __launch_bounds__(256) void k_kp_ctx(
    const float* __restrict__ kdbuf, const float* __restrict__ vbuf,
    const _Float16* __restrict__ pjh, const _Float16* __restrict__ pjl,
    const unsigned int* __restrict__ kmaxu,
    float* __restrict__ ksum_g, float* __restrict__ ctxT_g) {
  __shared__ float ctxred[32][113];
  const int tid = threadIdx.x, w = tid >> 6, l = tid & 63;
  const int lr = l & 15, lg = l >> 4;
  const int tok0 = blockIdx.x * 512;
  const int b = tok0 >> 14;
  unsigned mu = *kmaxu;
  float M = (mu & 0x80000000u) ? __uint_as_float(mu ^ 0x80000000u) : __uint_as_float(~mu);

  for (int hh = 0; hh < 2; hh++) {
    for (int i = tid; i < 32 * 113; i += 256) ((float*)ctxred)[i] = 0.f;
    float ksumacc[7];
#pragma unroll
    for (int nf = 0; nf < 7; nf++) ksumacc[nf] = 0.f;
    f32x4 ctxacc[2][7];
#pragma unroll
    for (int mtD = 0; mtD < 2; mtD++)
#pragma unroll
      for (int nf = 0; nf < 7; nf++) ctxacc[mtD][nf] = f32x4{0.f, 0.f, 0.f, 0.f};
    __syncthreads();

    for (int it = 0; it < 4; it++) {
      const int tb = tok0 + it * 128 + w * 32;
      f16x8 kAh[2], kAl[2];
      float diagv[2];
#pragma unroll
      for (int mtT = 0; mtT < 2; mtT++) {
        const float* kp_ = kdbuf + (size_t)(tb + mtT * 16 + lr) * 64 + hh * 32 + lg * 8;
        float4 a0 = *(const float4*)kp_;
        float4 a1 = *(const float4*)(kp_ + 4);
        float kv[8] = {a0.x, a0.y, a0.z, a0.w, a1.x, a1.y, a1.z, a1.w};
        float p = 0.f;
#pragma unroll
        for (int e = 0; e < 8; e++) {
          _Float16 hi = (_Float16)kv[e];
          kAh[mtT][e] = hi; kAl[mtT][e] = (_Float16)(kv[e] - (float)hi);
          p += kv[e] * kv[e];
        }
        p += __shfl_xor(p, 16); p += __shfl_xor(p, 32);
        diagv[mtT] = 0.5f * p;
      }
      float diagD[2][4];
#pragma unroll
      for (int mtT = 0; mtT < 2; mtT++)
#pragma unroll
        for (int r = 0; r < 4; r++)
          diagD[mtT][r] = __shfl(diagv[mtT], lg * 4 + r);
      f16x8 vAh[2], vAl[2];
#pragma unroll
      for (int mtD = 0; mtD < 2; mtD++) {
        const float* vp_ = vbuf + (size_t)(tb + lg * 8) * 64 + hh * 32 + mtD * 16 + lr;
#pragma unroll
        for (int e = 0; e < 8; e++) {
          float vv = vp_[(size_t)e * 64];
          _Float16 hi = (_Float16)vv;
          vAh[mtD][e] = hi; vAl[mtD][e] = (_Float16)(vv - (float)hi);
        }
      }
#pragma unroll
      for (int nf = 0; nf < 7; nf++) {
        f16x8 bh = *(const f16x8*)(pjh + ((nf * 64 + l) << 3));
        f16x8 bl = *(const f16x8*)(pjl + ((nf * 64 + l) << 3));
        float kpe[2][4];
#pragma unroll
        for (int mtT = 0; mtT < 2; mtT++) {
          f32x4 dd = f32x4{0.f, 0.f, 0.f, 0.f};
          dd = __builtin_amdgcn_mfma_f32_16x16x32_f16(kAh[mtT], bh, dd, 0, 0, 0);
          dd = __builtin_amdgcn_mfma_f32_16x16x32_f16(kAh[mtT], bl, dd, 0, 0, 0);
          dd = __builtin_amdgcn_mfma_f32_16x16x32_f16(kAl[mtT], bh, dd, 0, 0, 0);
#pragma unroll
          for (int r = 0; r < 4; r++) {
            float e_ = RATIO * (__expf(dd[r] - diagD[mtT][r] - M) + KEPS);
            if (nf == 6 && lr >= 14) e_ = 0.f;
            kpe[mtT][r] = e_;
            ksumacc[nf] += e_;
          }
        }
        f16x8 pbh, pbl;
#pragma unroll
        for (int e = 0; e < 8; e++) {
          int srcl = lr + ((((lg << 1) + (e >> 2)) & 3) << 4);
          float v0 = __shfl(kpe[0][e & 3], srcl);
          float v1 = __shfl(kpe[1][e & 3], srcl);
          float val = (lg >= 2) ? v1 : v0;
          _Float16 hi = (_Float16)val;
          pbh[e] = hi; pbl[e] = (_Float16)(val - (float)hi);
        }
#pragma unroll
        for (int mtD = 0; mtD < 2; mtD++) {
          ctxacc[mtD][nf] = __builtin_amdgcn_mfma_f32_16x16x32_f16(vAh[mtD], pbh, ctxacc[mtD][nf], 0, 0, 0);
          ctxacc[mtD][nf] = __builtin_amdgcn_mfma_f32_16x16x32_f16(vAh[mtD], pbl, ctxacc[mtD][nf], 0, 0, 0);
          ctxacc[mtD][nf] = __builtin_amdgcn_mfma_f32_16x16x32_f16(vAl[mtD], pbh, ctxacc[mtD][nf], 0, 0, 0);
        }
      }
    }
#pragma unroll
    for (int nf = 0; nf < 7; nf++) {
      float s = ksumacc[nf];
      s += __shfl_xor(s, 16); s += __shfl_xor(s, 32);
      int f = nf * 16 + lr;
      if (lg == 0 && f < F_) atomicAdd(&ksum_g[(b * 2 + hh) * F_ + f], s);
    }
#pragma unroll
    for (int mtD = 0; mtD < 2; mtD++)
#pragma unroll
      for (int nf = 0; nf < 7; nf++)
#pragma unroll
        for (int r = 0; r < 4; r++)
          atomicAdd(&ctxred[mtD * 16 + lg * 4 + r][nf * 16 + lr], ctxacc[mtD][nf][r]);
    __syncthreads();
    for (int i = tid; i < 32 * 112; i += 256) {
      int d = i / 112, f = i - d * 112;
      atomicAdd(&ctxT_g[((size_t)(b * 2 + hh) * 32 + d) * 112 + f], ctxred[d][f]);
    }
    __syncthreads();
  }
}

// ====== merged MFMA attention: LN1+Qproj+features+o, then wo+LN2+FF ======
// Chunked LDS staging: scrB holds only a 64-col K-slab of qp/t1 at a time.
__global__ __launch_bounds__(256) void k_attn(
    float* __restrict__ hbuf,
    const _Float16* __restrict__ whi, const _Float16* __restrict__ wlo,  // layer base
    const _Float16* __restrict__ ctxBh, const _Float16* __restrict__ ctxBl,
    const float* __restrict__ ksum_g,
    const float* __restrict__ ln1g, const float* __restrict__ ln1b,
    const float* __restrict__ bq,  const float* __restrict__ bo,
    const float* __restrict__ ln2g, const float* __restrict__ ln2b,
    const float* __restrict__ b1,  const float* __restrict__ b2) {
  __shared__ __align__(16) unsigned char scrA_[4][4992];  // q h/l [16][72] -> o f32 [16][76] -> y h/l [16][72]
  __shared__ __align__(16) unsigned char scrB_[4][4608];  // qp/t1 64-col chunk h/l [16][72]
  const int tid = threadIdx.x, w = tid >> 6, l = tid & 63;
  const int lr = l & 15, lg = l >> 4;
  const int row0 = blockIdx.x * 64 + w * 16;
  const int b = (blockIdx.x * 64) >> 14;
  _Float16* qh = (_Float16*)scrA_[w];
  _Float16* ql = qh + 16 * 72;
  float*    oS = (float*)scrA_[w];
  _Float16* yh = (_Float16*)scrA_[w];
  _Float16* yl = yh + 16 * 72;
  _Float16* ph = (_Float16*)scrB_[w];
  _Float16* pl = ph + 16 * 72;

  // ---- LN1, distributed ----
  float hv[16];
#pragma unroll
  for (int kb = 0; kb < 2; kb++) {
    const float* hp = hbuf + (size_t)(row0 + lr) * 64 + kb * 32 + lg * 8;
    float4 p0 = *(const float4*)hp;
    float4 p1 = *(const float4*)(hp + 4);
    hv[kb * 8 + 0] = p0.x; hv[kb * 8 + 1] = p0.y; hv[kb * 8 + 2] = p0.z; hv[kb * 8 + 3] = p0.w;
    hv[kb * 8 + 4] = p1.x; hv[kb * 8 + 5] = p1.y; hv[kb * 8 + 6] = p1.z; hv[kb * 8 + 7] = p1.w;
  }
  float s = 0.f;
#pragma unroll
  for (int i = 0; i < 16; i++) s += hv[i];
  s += __shfl_xor(s, 16); s += __shfl_xor(s, 32);
  float mu1 = s * (1.f / 64.f);
  float sq = 0.f;
#pragma unroll
  for (int i = 0; i < 16; i++) { float d = hv[i] - mu1; sq += d * d; }
  sq += __shfl_xor(sq, 16); sq += __shfl_xor(sq, 32);
  float rs1 = rsqrtf(sq * (1.f / 64.f) + 1e-5f);
  f16x8 ah1[2], al1[2];
#pragma unroll
  for (int kb = 0; kb < 2; kb++) {
    const float* gp = ln1g + kb * 32 + lg * 8;
    const float* bp = ln1b + kb * 32 + lg * 8;
    float4 g0 = *(const float4*)gp, g1 = *(const float4*)(gp + 4);
    float4 b0 = *(const float4*)bp, b1v_ = *(const float4*)(bp + 4);
    float gv[8] = {g0.x, g0.y, g0.z, g0.w, g1.x, g1.y, g1.z, g1.w};
    float bv[8] = {b0.x, b0.y, b0.z, b0.w, b1v_.x, b1v_.y, b1v_.z, b1v_.w};
#pragma unroll
    for (int e = 0; e < 8; e++) {
      float yv = (hv[kb * 8 + e] - mu1) * rs1 * gv[e] + bv[e];
      _Float16 hi = (_Float16)yv;
      ah1[kb][e] = hi;
      al1[kb][e] = (_Float16)(yv - (float)hi);
    }
  }
  // ---- q = y1 @ wq + bq, *DN ----
  const _Float16* wqh = whi + 36864; const _Float16* wql = wlo + 36864;
  f32x4 q[4];
#pragma unroll
  for (int nt = 0; nt < 4; nt++) {
    float bb = bq[nt * 16 + lr];
    q[nt] = f32x4{bb, bb, bb, bb};
  }
#pragma unroll
  for (int kb = 0; kb < 2; kb++)
#pragma unroll
    for (int nt = 0; nt < 4; nt++) {
      int f = kb * 4 + nt;
      f16x8 bh = *(const f16x8*)(wqh + ((f * 64 + l) << 3));
      f16x8 bl = *(const f16x8*)(wql + ((f * 64 + l) << 3));
      q[nt] = __builtin_amdgcn_mfma_f32_16x16x32_f16(ah1[kb], bh, q[nt], 0, 0, 0);
      q[nt] = __builtin_amdgcn_mfma_f32_16x16x32_f16(ah1[kb], bl, q[nt], 0, 0, 0);
      q[nt] = __builtin_amdgcn_mfma_f32_16x16x32_f16(al1[kb], bh, q[nt], 0, 0, 0);
    }
#pragma unroll
  for (int nt = 0; nt < 4; nt++)
#pragma unroll
    for (int r = 0; r < 4; r++) q[nt][r] *= DN;
  float diag[2][4];
#pragma unroll
  for (int hh = 0; hh < 2; hh++)
#pragma unroll
    for (int r = 0; r < 4; r++) {
      float t = q[hh * 2][r] * q[hh * 2][r] + q[hh * 2 + 1][r] * q[hh * 2 + 1][r];
      diag[hh][r] = 0.5f * rsum16(t);
    }
#pragma unroll
  for (int nt = 0; nt < 4; nt++)
#pragma unroll
    for (int r = 0; r < 4; r++) {
      float v = q[nt][r];
      _Float16 hi = (_Float16)v;
      qh[(lg * 4 + r) * 72 + nt * 16 + lr] = hi;
      ql[(lg * 4 + r) * 72 + nt * 16 + lr] = (_Float16)(v - (float)hi);
    }
  // ---- per head: dd, max, qp (chunked) -> o = qp@ctx ----
  const _Float16* pjh = whi + 40960; const _Float16* pjl = wlo + 40960;
  float dinv[2][4];
  f32x4 oreg[2][2];
#pragma unroll
  for (int hh = 0; hh < 2; hh++) {
    f16x8 aqh = *(const f16x8*)(qh + lr * 72 + hh * 32 + lg * 8);
    f16x8 aql = *(const f16x8*)(ql + lr * 72 + hh * 32 + lg * 8);
    f32x4 dd[7];
#pragma unroll
    for (int nt = 0; nt < 7; nt++) {
      dd[nt] = f32x4{0.f, 0.f, 0.f, 0.f};
      f16x8 bh = *(const f16x8*)(pjh + ((nt * 64 + l) << 3));
      f16x8 bl = *(const f16x8*)(pjl + ((nt * 64 + l) << 3));
      dd[nt] = __builtin_amdgcn_mfma_f32_16x16x32_f16(aqh, bh, dd[nt], 0, 0, 0);
      dd[nt] = __builtin_amdgcn_mfma_f32_16x16x32_f16(aqh, bl, dd[nt], 0, 0, 0);
      dd[nt] = __builtin_amdgcn_mfma_f32_16x16x32_f16(aql, bh, dd[nt], 0, 0, 0);
    }
    float mrow[4];
#pragma unroll
    for (int r = 0; r < 4; r++) {
      float m = dd[0][r];
#pragma unroll
      for (int nt = 1; nt < 6; nt++) m = fmaxf(m, dd[nt][r]);
      float v6 = (lr < 14) ? dd[6][r] : -3.0e38f;
      mrow[r] = rmax16(fmaxf(m, v6));
    }
    float ks[7];
#pragma unroll
    for (int nt = 0; nt < 7; nt++) {
      int f = nt * 16 + lr;
      ks[nt] = (f < F_) ? ksum_g[(b * 2 + hh) * F_ + f] : 0.f;
    }
    float sp[4] = {0.f, 0.f, 0.f, 0.f};
#pragma unroll
    for (int nt = 0; nt < 2; nt++) oreg[hh][nt] = f32x4{0.f, 0.f, 0.f, 0.f};
#pragma unroll
    for (int c = 0; c < 2; c++) {
      // stage 64-col chunk of qp (cols c*64 .. c*64+63, local stride 72)
#pragma unroll
      for (int ntl = 0; ntl < 4; ntl++) {
        const int nt = c * 4 + ntl;
        float ev[4];
        if (nt < 7) {
#pragma unroll
          for (int r = 0; r < 4; r++) {
            float e = 0.f;
            if (nt < 6 || lr < 14)
              e = RATIO * (__expf(dd[nt][r] - diag[hh][r] - mrow[r]) + KEPS);
            sp[r] += e * ks[nt];
            ev[r] = e;
          }
        } else {
#pragma unroll
          for (int r = 0; r < 4; r++) ev[r] = 0.f;
        }
#pragma unroll
        for (int r = 0; r < 4; r++) {
          _Float16 hi = (_Float16)ev[r];
          ph[(lg * 4 + r) * 72 + ntl * 16 + lr] = hi;
          pl[(lg * 4 + r) * 72 + ntl * 16 + lr] = (_Float16)(ev[r] - (float)hi);
        }
      }
      // consume chunk: o partial over this 64-K slab
#pragma unroll
      for (int kbl = 0; kbl < 2; kbl++) {
        f16x8 aph = *(const f16x8*)(ph + lr * 72 + kbl * 32 + lg * 8);
        f16x8 apl = *(const f16x8*)(pl + lr * 72 + kbl * 32 + lg * 8);
        const int kb = c * 2 + kbl;
#pragma unroll
        for (int nt2 = 0; nt2 < 2; nt2++) {
          size_t fi = (size_t)(((b * 2 + hh) * 8 + kb * 2 + nt2) * 64 + l) * 8;
          f16x8 bh = *(const f16x8*)(ctxBh + fi);
          f16x8 bl = *(const f16x8*)(ctxBl + fi);
          oreg[hh][nt2] = __builtin_amdgcn_mfma_f32_16x16x32_f16(aph, bh, oreg[hh][nt2], 0, 0, 0);
          oreg[hh][nt2] = __builtin_amdgcn_mfma_f32_16x16x32_f16(aph, bl, oreg[hh][nt2], 0, 0, 0);
          oreg[hh][nt2] = __builtin_amdgcn_mfma_f32_16x16x32_f16(apl, bh, oreg[hh][nt2], 0, 0, 0);
        }
      }
    }
#pragma unroll
    for (int r = 0; r < 4; r++) dinv[hh][r] = 1.f / rsum16(sp[r]);
  }
  // ---- o*dinv -> scratch f32 [16][76] (q area now dead) ----
#pragma unroll
  for (int hh = 0; hh < 2; hh++)
#pragma unroll
    for (int nt = 0; nt < 2; nt++)
#pragma unroll
      for (int r = 0; r < 4; r++)
        oS[(lg * 4 + r) * 76 + hh * 32 + nt * 16 + lr] = oreg[hh][nt][r] * dinv[hh][r];
  // ---- G1: D1 = o @ wo (+bo) ----
  f32x4 acc1[4];
#pragma unroll
  for (int nt = 0; nt < 4; nt++) {
    float bb = bo[nt * 16 + lr];
    acc1[nt] = f32x4{bb, bb, bb, bb};
  }
#pragma unroll
  for (int kb = 0; kb < 2; kb++) {
    float4 o0 = *(const float4*)(oS + lr * 76 + kb * 32 + lg * 8);
    float4 o1 = *(const float4*)(oS + lr * 76 + kb * 32 + lg * 8 + 4);
    float ov[8] = {o0.x, o0.y, o0.z, o0.w, o1.x, o1.y, o1.z, o1.w};
    f16x8 aoh, aol;
#pragma unroll
    for (int e = 0; e < 8; e++) {
      _Float16 hi = (_Float16)ov[e];
      aoh[e] = hi; aol[e] = (_Float16)(ov[e] - (float)hi);
    }
#pragma unroll
    for (int nt = 0; nt < 4; nt++) {
      int f = kb * 4 + nt;
      f16x8 bh = *(const f16x8*)(whi + ((f * 64 + l) << 3));
      f16x8 bl = *(const f16x8*)(wlo + ((f * 64 + l) << 3));
      acc1[nt] = __builtin_amdgcn_mfma_f32_16x16x32_f16(aoh, bh, acc1[nt], 0, 0, 0);
      acc1[nt] = __builtin_amdgcn_mfma_f32_16x16x32_f16(aoh, bl, acc1[nt], 0, 0, 0);
      acc1[nt] = __builtin_amdgcn_mfma_f32_16x16x32_f16(aol, bh, acc1[nt], 0, 0, 0);
    }
  }
  // ---- residual + LN2 ----
  float hA[4][4];
#pragma unroll
  for (int nt = 0; nt < 4; nt++)
#pragma unroll
    for (int r = 0; r < 4; r++)
      hA[nt][r] = hbuf[(size_t)(row0 + lg * 4 + r) * 64 + nt * 16 + lr] + acc1[nt][r];
  float mu2[4], rs2[4];
#pragma unroll
  for (int r = 0; r < 4; r++) {
    float t = hA[0][r] + hA[1][r] + hA[2][r] + hA[3][r];
    mu2[r] = rsum16(t) * (1.f / 64.f);
  }
#pragma unroll
  for (int r = 0; r < 4; r++) {
    float t = 0.f;
#pragma unroll
    for (int nt = 0; nt < 4; nt++) { float d = hA[nt][r] - mu2[r]; t += d * d; }
    rs2[r] = rsqrtf(rsum16(t) * (1.f / 64.f) + 1e-5f);
  }
#pragma unroll
  for (int nt = 0; nt < 4; nt++) {
    float gc = ln2g[nt * 16 + lr], bc = ln2b[nt * 16 + lr];
#pragma unroll
    for (int r = 0; r < 4; r++) {
      float yv = (hA[nt][r] - mu2[r]) * rs2[r] * gc + bc;
      _Float16 hi = (_Float16)yv;
      yh[(lg * 4 + r) * 72 + nt * 16 + lr] = hi;
      yl[(lg * 4 + r) * 72 + nt * 16 + lr] = (_Float16)(yv - (float)hi);
    }
  }
  // ---- FF in four 64-col quarters (t1 staged per quarter) ----
  const _Float16* w1h = whi + 4096;  const _Float16* w1l = wlo + 4096;
  const _Float16* w2h = whi + 20480; const _Float16* w2l = wlo + 20480;
  f32x4 acc3[4];
#pragma unroll
  for (int nt = 0; nt < 4; nt++) {
    float bb = b2[nt * 16 + lr];
    acc3[nt] = f32x4{bb, bb, bb, bb};
  }
  for (int qd = 0; qd < 4; qd++) {
    f32x4 acc2[4];
#pragma unroll
    for (int ntl = 0; ntl < 4; ntl++) {
      float bb = b1[qd * 64 + ntl * 16 + lr];
      acc2[ntl] = f32x4{bb, bb, bb, bb};
    }
#pragma unroll
    for (int kb = 0; kb < 2; kb++) {
      f16x8 ayh = *(const f16x8*)(yh + lr * 72 + kb * 32 + lg * 8);
      f16x8 ayl = *(const f16x8*)(yl + lr * 72 + kb * 32 + lg * 8);
#pragma unroll
      for (int ntl = 0; ntl < 4; ntl++) {
        int f = kb * 16 + qd * 4 + ntl;
        f16x8 bh = *(const f16x8*)(w1h + ((f * 64 + l) << 3));
        f16x8 bl = *(const f16x8*)(w1l + ((f * 64 + l) << 3));
        acc2[ntl] = __builtin_amdgcn_mfma_f32_16x16x32_f16(ayh, bh, acc2[ntl], 0, 0, 0);
        acc2[ntl] = __builtin_amdgcn_mfma_f32_16x16x32_f16(ayh, bl, acc2[ntl], 0, 0, 0);
        acc2[ntl] = __builtin_amdgcn_mfma_f32_16x16x32_f16(ayl, bh, acc2[ntl], 0, 0, 0);
      }
    }
    // GELU + stage quarter
#pragma unroll
    for (int ntl = 0; ntl < 4; ntl++)
#pragma unroll
      for (int r = 0; r < 4; r++) {
        float t = acc2[ntl][r];
        float gl = 0.5f * t * (1.f + erff(t * 0.70710678118654752f));
        _Float16 hi = (_Float16)gl;
        ph[(lg * 4 + r) * 72 + ntl * 16 + lr] = hi;
        pl[(lg * 4 + r) * 72 + ntl * 16 + lr] = (_Float16)(gl - (float)hi);
      }
    // G3 partial over this quarter's K-range
#pragma unroll
    for (int kb2l = 0; kb2l < 2; kb2l++) {
      f16x8 ath = *(const f16x8*)(ph + lr * 72 + kb2l * 32 + lg * 8);
      f16x8 atl = *(const f16x8*)(pl + lr * 72 + kb2l * 32 + lg * 8);
      const int kb2 = qd * 2 + kb2l;
#pragma unroll
      for (int nt = 0; nt < 4; nt++) {
        int f = kb2 * 4 + nt;
        f16x8 bh = *(const f16x8*)(w2h + ((f * 64 + l) << 3));
        f16x8 bl = *(const f16x8*)(w2l + ((f * 64 + l) << 3));
        acc3[nt] = __builtin_amdgcn_mfma_f32_16x16x32_f16(ath, bh, acc3[nt], 0, 0, 0);
        acc3[nt] = __builtin_amdgcn_mfma_f32_16x16x32_f16(ath, bl, acc3[nt], 0, 0, 0);
        acc3[nt] = __builtin_amdgcn_mfma_f32_16x16x32_f16(atl, bh, acc3[nt], 0, 0, 0);
      }
    }
  }
#pragma unroll
  for (int nt = 0; nt < 4; nt++)
#pragma unroll
    for (int r = 0; r < 4; r++)
      hbuf[(size_t)(row0 + lg * 4 + r) * 64 + nt * 16 + lr] = hA[nt][r] + acc3[nt][r];
}

// ---------------- mean over N (partial) ----------------
__global__ __launch_bounds__(256) void k_colsum(const float* __restrict__ hbuf,
                                                float* __restrict__ colsum) {
  __shared__ float red[256];
  int bb = blockIdx.x >> 3, chunk = blockIdx.x & 7;
  int t = threadIdx.x;
  int c = t & 63, r0 = t >> 6;
  size_t base = ((size_t)bb * N_ + chunk * 2048 + r0) * 64 + c;
  float acc = 0.f;
  for (int s = 0; s < 512; s++) acc += hbuf[base + (size_t)s * 256];
  red[t] = acc;
  __syncthreads();
  if (t < 64) {
    float tot = red[t] + red[t + 64] + red[t + 128] + red[t + 192];
    atomicAdd(&colsum[bb * 64 + t], tot);
  }
}

// ---------------- classifier ----------------
__global__ __launch_bounds__(128) void k_logits(const float* __restrict__ colsum,
                                                const float* __restrict__ cw,
                                                const float* __restrict__ cb,
                                                float* __restrict__ out) {
  int t = threadIdx.x;
  if (t < 80) {
    int b = t / 10, kk = t - b * 10;
    float acc = 0.f;
    for (int c = 0; c < 64; c++) acc += colsum[b * 64 + c] * cw[c * 10 + kk];
    out[t] = acc * (1.f / 16384.f) + cb[kk];
  }
}

extern "C" void kernel_launch(void* const* d_in, const int* in_sizes, int n_in,
                              void* d_out, int out_size, void* d_ws, size_t ws_size,
                              hipStream_t stream) {
  const float* x    = (const float*)d_in[0];
  const float* emb  = (const float*)d_in[1];
  const float* ln1g = (const float*)d_in[2];
  const float* ln1b = (const float*)d_in[3];
  const float* wq   = (const float*)d_in[4];
  const float* bq   = (const float*)d_in[5];
  const float* wk   = (const float*)d_in[6];
  const float* bk   = (const float*)d_in[7];
  const float* wv   = (const float*)d_in[8];
  const float* bv   = (const float*)d_in[9];
  const float* wo   = (const float*)d_in[10];
  const float* bo   = (const float*)d_in[11];
  const float* proj = (const float*)d_in[12];
  const float* ln2g = (const float*)d_in[13];
  const float* ln2b = (const float*)d_in[14];
  const float* w1   = (const float*)d_in[15];
  const float* b1   = (const float*)d_in[16];
  const float* w2   = (const float*)d_in[17];
  const float* b2   = (const float*)d_in[18];
  const float* cw   = (const float*)d_in[19];
  const float* cb   = (const float*)d_in[20];

  float* h      = (float*)d_ws;                   // NTOK*64
  float* kb     = h + (size_t)NTOK * 64;          // NTOK*64 (k*dn)
  float* vb     = kb + (size_t)NTOK * 64;         // NTOK*64
  float* ctx    = vb + (size_t)NTOK * 64;         // ctxT: 16*32*112
  float* ksum   = ctx + CTXE;                     // 16*110
  unsigned* kmaxu = (unsigned*)(ksum + 16 * F_);  // 1
  float* colsum = (float*)(kmaxu + 1);            // 512
  uintptr_t wp = (uintptr_t)(colsum + 512);
  wp = (wp + 63) & ~(uintptr_t)63;
  _Float16* whi   = (_Float16*)wp;                // 4*WSEG
  _Float16* wlo   = whi + 4 * WSEG;               // 4*WSEG
  _Float16* ctxBh = wlo + 4 * WSEG;               // 65536
  _Float16* ctxBl = ctxBh + 65536;                // 65536

  hipMemsetAsync(ctx, 0, (size_t)(CTXE + 16 * F_ + 1 + 512) * sizeof(float), stream);
  k_prep<<<(4 * WSEG) / 256, 256, 0, stream>>>(wo, w1, w2, wq, proj, wk, wv, whi, wlo);
  k_embed<<<NTOK * 64 / 256, 256, 0, stream>>>(x, emb, h);
  for (int l = 0; l < 4; l++) {
    if (l) hipMemsetAsync(ctx, 0, (size_t)(CTXE + 16 * F_ + 1) * sizeof(float), stream);
    k_ln_kv<<<NTOK / 64, 256, 0, stream>>>(h, ln1g + 64 * l, ln1b + 64 * l,
                                           whi + (size_t)l * WSEG, wlo + (size_t)l * WSEG,
                                           bk + 64 * l, bv + 64 * l, kb, vb, kmaxu);
    k_kp_ctx<<<NTOK / 512, 256, 0, stream>>>(kb, vb,
                                             whi + (size_t)l * WSEG + 40960,
                                             wlo + (size_t)l * WSEG + 40960,
                                             kmaxu, ksum, ctx);
    k_ctxprep<<<256, 256, 0, stream>>>(ctx, ctxBh, ctxBl);
    k_attn<<<NTOK / 64, 256, 0, stream>>>(h, whi + (size_t)l * WSEG, wlo + (size_t)l * WSEG,
                                          ctxBh, ctxBl, ksum,
                                          ln1g + 64 * l, ln1b + 64 * l, bq + 64 * l,
                                          bo + 64 * l, ln2g + 64 * l, ln2b + 64 * l,
                                          b1 + 256 * l, b2 + 64 * l);
  }
  k_colsum<<<64, 256, 0, stream>>>(h, colsum);
  k_logits<<<1, 128, 0, stream>>>(colsum, cw, cb, (float*)d_out);
}